// Round 13
// baseline (121.344 us; speedup 1.0000x reference)
//
#include <hip/hip_runtime.h>

// MMoE: B=16384 D=512 U=128 E=16 T=4, fp32 in/out.
// vs round-12 (PASSING, 100.7us): ONE change — moe staging switches from
// reg-stage(+pad) to global_load_lds with linear [row][64] LDS tiles
// (LDA/LDB 72->64). Same bf16 values at new LDS addresses; MFMA inputs
// bit-identical. gates/convert_ek/swizzle/epilogue: r12 VERBATIM.
// ws: gates 4MiB @0, xb 16MiB @4MiB, ekT 2MiB @20MiB.

#define Bsz 16384
#define Dd  512
#define Uu  128
#define Ee  16
#define Tt  4
#define Nn  2048   // U*E

typedef short bf16x8 __attribute__((ext_vector_type(8)));
typedef float f32x4 __attribute__((ext_vector_type(4)));
typedef unsigned short u16x8 __attribute__((ext_vector_type(8)));

static __device__ __forceinline__ unsigned short f2bf(float f) {
    unsigned int u = __builtin_bit_cast(unsigned int, f);
    u += 0x7fffu + ((u >> 16) & 1u);   // round-to-nearest-even
    return (unsigned short)(u >> 16);
}
static __device__ __forceinline__ float bf2f(unsigned short s) {
    return __builtin_bit_cast(float, (unsigned int)s << 16);
}

#define GLOAD16(g, l) __builtin_amdgcn_global_load_lds( \
    (const __attribute__((address_space(1))) void*)(g), \
    (__attribute__((address_space(3))) void*)(l), 16, 0, 0)

// ---------------- Kernel 0: ek -> ekT bf16 transpose (r10-12 verbatim) ----------------
__global__ __launch_bounds__(256) void convert_ek(
        const float* __restrict__ ek, unsigned short* __restrict__ ekT) {
    __shared__ unsigned short ts[64 * 65];
    const int bx = blockIdx.x, tid = threadIdx.x;
    const int n0 = (bx & 31) * 64, d0 = (bx >> 5) * 64;
    #pragma unroll
    for (int i = 0; i < 4; ++i) {
        int flat = i * 256 + tid;
        int dl = flat >> 4, ng = (flat & 15) * 4;
        const float4 v = *(const float4*)(ek + (size_t)(d0 + dl) * Nn + n0 + ng);
        ts[(ng + 0) * 65 + dl] = f2bf(v.x);
        ts[(ng + 1) * 65 + dl] = f2bf(v.y);
        ts[(ng + 2) * 65 + dl] = f2bf(v.z);
        ts[(ng + 3) * 65 + dl] = f2bf(v.w);
    }
    __syncthreads();
    #pragma unroll
    for (int i = 0; i < 4; ++i) {
        int flat = i * 256 + tid;
        int nl = flat >> 4, dg = (flat & 15) * 4;
        ushort4 w = make_ushort4(ts[nl * 65 + dg], ts[nl * 65 + dg + 1],
                                 ts[nl * 65 + dg + 2], ts[nl * 65 + dg + 3]);
        *(ushort4*)(ekT + (size_t)(n0 + nl) * Dd + d0 + dg) = w;
    }
}

// ---------------- Kernel 1: gates + fused x->bf16 conversion (r12 verbatim) ----------------
__global__ __launch_bounds__(256) void gates_kernel(
        const float* __restrict__ x, const float* __restrict__ gk,
        const float* __restrict__ gb, float* __restrict__ gates,
        unsigned short* __restrict__ xb) {
    __shared__ __align__(16) float xl[16][128];    // 8 KB
    __shared__ __align__(16) float gkl[128][64];   // 32 KB
    const int tid = threadIdx.x;
    const int w = tid >> 6, lane = tid & 63;
    const int b0 = blockIdx.x * 16;
    float acc[4] = {0.f, 0.f, 0.f, 0.f};

    for (int c = 0; c < 4; ++c) {
        const int d0 = c * 128;
        __syncthreads();  // previous chunk consumed
        #pragma unroll
        for (int p = 0; p < 2; ++p) {
            const int flat = p * 256 + tid;
            const int row = flat >> 5, c4 = (flat & 31) * 4;
            const float4 v =
                *(const float4*)(x + (size_t)(b0 + row) * Dd + d0 + c4);
            *(float4*)(&xl[row][c4]) = v;
            *(ushort4*)(xb + (size_t)(b0 + row) * Dd + d0 + c4) =
                make_ushort4(f2bf(v.x), f2bf(v.y), f2bf(v.z), f2bf(v.w));
        }
        {
            const int n = tid & 63, dl0 = tid >> 6;
            const float* gp = gk + (size_t)(n >> 4) * (Dd * Ee) + (n & 15)
                                 + (size_t)(d0 + dl0) * Ee;
            #pragma unroll
            for (int j = 0; j < 32; ++j)
                gkl[dl0 + j * 4][n] = gp[(size_t)j * 4 * Ee];
        }
        __syncthreads();
        #pragma unroll 4
        for (int dq = 0; dq < 32; ++dq) {
            float wv[4];
            #pragma unroll
            for (int q = 0; q < 4; ++q) wv[q] = gkl[dq * 4 + q][lane];
            #pragma unroll
            for (int r = 0; r < 4; ++r) {
                const float4 xv = *(const float4*)(&xl[w * 4 + r][dq * 4]);
                float a = acc[r];
                a = fmaf(xv.x, wv[0], a);
                a = fmaf(xv.y, wv[1], a);
                a = fmaf(xv.z, wv[2], a);
                a = fmaf(xv.w, wv[3], a);
                acc[r] = a;
            }
        }
    }
    const float bias = gb[lane];
    #pragma unroll
    for (int r = 0; r < 4; ++r) {
        float a = acc[r] + bias;
        float m = a;
        m = fmaxf(m, __shfl_xor(m, 1));
        m = fmaxf(m, __shfl_xor(m, 2));
        m = fmaxf(m, __shfl_xor(m, 4));
        m = fmaxf(m, __shfl_xor(m, 8));
        float p = __expf(a - m);
        float s = p;
        s += __shfl_xor(s, 1);
        s += __shfl_xor(s, 2);
        s += __shfl_xor(s, 4);
        s += __shfl_xor(s, 8);
        gates[(size_t)(b0 + w * 4 + r) * 64 + lane] = p / s;  // [b][t*16+e]
    }
}

// ---------------- Kernel 2: expert GEMM + relu + gate contraction ----------------
// r12 structure; staging via global_load_lds into LINEAR [row][64] tiles.
#define BM 128
#define BN 256   // = 16 u's x 16 e's (n = u*16+e)
#define BK 64
#define LDE 264

__global__ __launch_bounds__(512) void moe_kernel(
        const unsigned short* __restrict__ xb,
        const unsigned short* __restrict__ ekT,
        const float* __restrict__ eb, const float* __restrict__ gates,
        float* __restrict__ out) {
    __shared__ __align__(16) unsigned short smem[BM * LDE];  // 67584 B
    unsigned short* sA = smem;            // [128][64] linear (16 KB)
    unsigned short* sB = smem + 8192;     // [256][64] linear (32 KB)

    const int tid = threadIdx.x;
    const int wave = tid >> 6, lane = tid & 63;
    const int llo = lane & 15, lhi = lane >> 4;
    // XCD swizzle (r12 verbatim): bijective for 1024 blocks.
    const int g = (blockIdx.x & 7) * 128 + (blockIdx.x >> 3);
    const int b0 = (g >> 3) * BM;
    const int n0 = (g & 7) * BN;
    const int mr = (wave >> 2) * 64;  // wave row origin
    const int nc = (wave & 3) * 64;   // wave col origin

    f32x4 acc[4][4] = {};

    for (int kt = 0; kt < Dd / BK; ++kt) {
        const int k0 = kt * BK;
        __syncthreads();  // previous tile fully consumed before overwrite
        // stage A: 1024 16B-chunks; chunk c = cb + lane, cb uniform per call.
        #pragma unroll
        for (int i = 0; i < 2; ++i) {
            const int cb = i * 512 + wave * 64;
            const int c = cb + lane;
            GLOAD16(xb + (size_t)(b0 + (c >> 3)) * Dd + k0 + (c & 7) * 8,
                    sA + cb * 8);
        }
        // stage B: 2048 16B-chunks.
        #pragma unroll
        for (int i = 0; i < 4; ++i) {
            const int cb = i * 512 + wave * 64;
            const int c = cb + lane;
            GLOAD16(ekT + (size_t)(n0 + (c >> 3)) * Dd + k0 + (c & 7) * 8,
                    sB + cb * 8);
        }
        __syncthreads();  // compiler drains vmcnt before barrier
        #pragma unroll
        for (int ks = 0; ks < BK; ks += 32) {
            bf16x8 aF[4], bF[4];
            #pragma unroll
            for (int mi = 0; mi < 4; ++mi)
                aF[mi] = *(const bf16x8*)(sA + (mr + mi * 16 + llo) * 64 + ks + lhi * 8);
            #pragma unroll
            for (int ni = 0; ni < 4; ++ni)
                bF[ni] = *(const bf16x8*)(sB + (nc + ni * 16 + llo) * 64 + ks + lhi * 8);
            #pragma unroll
            for (int mi = 0; mi < 4; ++mi)
                #pragma unroll
                for (int ni = 0; ni < 4; ++ni)
                    acc[mi][ni] = __builtin_amdgcn_mfma_f32_16x16x32_bf16(
                        aF[mi], bF[ni], acc[mi][ni], 0, 0, 0);
        }
    }

    __syncthreads();  // all MFMA reads done; safe to overlay eo on staging LDS
    unsigned short* eo = smem;  // [BM][LDE] bf16 expert tile (relu'd)
    #pragma unroll
    for (int ni = 0; ni < 4; ++ni) {
        const int col = nc + ni * 16 + llo;     // C frag: col = lane&15
        const float ebv = eb[n0 + col];         // flat [u][e] == n
        #pragma unroll
        for (int mi = 0; mi < 4; ++mi) {
            #pragma unroll
            for (int j = 0; j < 4; ++j) {
                int row = mr + mi * 16 + lhi * 4 + j;  // C frag: row = (lane>>4)*4+j
                eo[row * LDE + col] = f2bf(fmaxf(acc[mi][ni][j] + ebv, 0.f));
            }
        }
    }
    __syncthreads();
    // contraction: out[t,b,u] = sum_e eo[b,u,e] * gates[b][t*16+e]
    #pragma unroll
    for (int i = 0; i < 4; ++i) {
        int f = i * 512 + tid;
        int m = f >> 4, ul = f & 15;
        const unsigned short* er = eo + m * LDE + ul * 16;
        const float* gr = gates + (size_t)(b0 + m) * 64;
        float o0 = 0.f, o1 = 0.f, o2 = 0.f, o3 = 0.f;
        #pragma unroll
        for (int e = 0; e < 16; ++e) {
            float v = bf2f(er[e]);
            o0 = fmaf(v, gr[e], o0);
            o1 = fmaf(v, gr[16 + e], o1);
            o2 = fmaf(v, gr[32 + e], o2);
            o3 = fmaf(v, gr[48 + e], o3);
        }
        size_t base = (size_t)(b0 + m) * Uu + (n0 >> 4) + ul;
        out[base] = o0;
        out[(size_t)Bsz * Uu + base] = o1;
        out[2 * (size_t)Bsz * Uu + base] = o2;
        out[3 * (size_t)Bsz * Uu + base] = o3;
    }
}

extern "C" void kernel_launch(void* const* d_in, const int* in_sizes, int n_in,
                              void* d_out, int out_size, void* d_ws, size_t ws_size,
                              hipStream_t stream) {
    const float* x  = (const float*)d_in[0];
    const float* ek = (const float*)d_in[1];
    const float* eb = (const float*)d_in[2];
    const float* gk = (const float*)d_in[3];
    const float* gb = (const float*)d_in[4];
    float* out = (float*)d_out;

    char* wsb = (char*)d_ws;
    float* gates       = (float*)wsb;                            // 4 MiB @ 0
    unsigned short* xb  = (unsigned short*)(wsb + (4u << 20));   // 16 MiB @ 4
    unsigned short* ekT = (unsigned short*)(wsb + (20u << 20));  // 2 MiB @ 20

    gates_kernel<<<Bsz / 16, 256, 0, stream>>>(x, gk, gb, gates, xb);
    convert_ek<<<256, 256, 0, stream>>>(ek, ekT);
    moe_kernel<<<1024, 512, 0, stream>>>(xb, ekT, eb, gates, out);
}